// Round 1
// baseline (412.338 us; speedup 1.0000x reference)
//
#include <hip/hip_runtime.h>
#include <math.h>

#define H 2048
#define G4 (4 * H)   // 8192 gate rows per layer

// One 64-lane wave computes one gate row:
//   gates[row] = dot(Wi[row,:], x) + dot(Wh[row,:], h) + bi[row] + bh[row]
// float4 loads: 64 lanes * 4 floats = 256 floats/iter, 8 iters over H=2048.
__global__ __launch_bounds__(256) void lstm_gates_kernel(
    const float* __restrict__ Wi,   // [4H, H] this layer
    const float* __restrict__ Wh,   // [4H, H] this layer
    const float* __restrict__ bi,   // [4H]
    const float* __restrict__ bh,   // [4H]
    const float* __restrict__ x,    // [H]
    const float* __restrict__ h,    // [H]
    float* __restrict__ gates)      // [4H] out (pre-activation)
{
    const int wave = (blockIdx.x * blockDim.x + threadIdx.x) >> 6;
    const int lane = threadIdx.x & 63;
    if (wave >= G4) return;

    const float4* wi4 = (const float4*)(Wi + (size_t)wave * H);
    const float4* wh4 = (const float4*)(Wh + (size_t)wave * H);
    const float4* x4  = (const float4*)x;
    const float4* h4  = (const float4*)h;

    float acc = 0.f;
#pragma unroll
    for (int it = 0; it < (H / 4) / 64; ++it) {   // 8 iterations
        const int idx = it * 64 + lane;
        float4 a = wi4[idx];
        float4 v = x4[idx];
        acc += a.x * v.x + a.y * v.y + a.z * v.z + a.w * v.w;
        float4 b = wh4[idx];
        float4 u = h4[idx];
        acc += b.x * u.x + b.y * u.y + b.z * u.z + b.w * u.w;
    }

    // 64-lane butterfly reduce
#pragma unroll
    for (int off = 32; off > 0; off >>= 1)
        acc += __shfl_down(acc, off);

    if (lane == 0)
        gates[wave] = acc + bi[wave] + bh[wave];
}

// Elementwise LSTM cell update over H elements.
__global__ __launch_bounds__(256) void lstm_update_kernel(
    const float* __restrict__ gates,  // [4H] pre-activation, order i,f,g,o
    const float* __restrict__ c0,     // [H] this layer
    float* __restrict__ h_next,       // [H] -> x for next layer (or d_out)
    float* __restrict__ out_extra)    // d_out on last layer, else nullptr
{
    const int j = blockIdx.x * blockDim.x + threadIdx.x;
    if (j >= H) return;

    const float gi = gates[j];
    const float gf = gates[H + j];
    const float gg = gates[2 * H + j];
    const float go = gates[3 * H + j];

    const float i_ = 1.f / (1.f + expf(-gi));
    const float f_ = 1.f / (1.f + expf(-gf));
    const float g_ = tanhf(gg);
    const float o_ = 1.f / (1.f + expf(-go));

    const float c_new = f_ * c0[j] + i_ * g_;
    const float h_new = o_ * tanhf(c_new);

    h_next[j] = h_new;
    if (out_extra) out_extra[j] = h_new;
}

extern "C" void kernel_launch(void* const* d_in, const int* in_sizes, int n_in,
                              void* d_out, int out_size, void* d_ws, size_t ws_size,
                              hipStream_t stream) {
    const float* x    = (const float*)d_in[0];  // [H]
    const float* W_ih = (const float*)d_in[1];  // [3, 4H, H]
    const float* W_hh = (const float*)d_in[2];  // [3, 4H, H]
    const float* b_ih = (const float*)d_in[3];  // [3, 4H]
    const float* b_hh = (const float*)d_in[4];  // [3, 4H]
    const float* h0   = (const float*)d_in[5];  // [3, H]
    const float* c0   = (const float*)d_in[6];  // [3, H]
    float* out = (float*)d_out;                 // [H]

    float* gates = (float*)d_ws;                // [4H]
    float* xbuf  = gates + G4;                  // [H]

    const size_t Wstride = (size_t)G4 * H;      // per-layer weight elements

    const float* cur_x = x;
    for (int l = 0; l < 3; ++l) {
        const bool last = (l == 2);
        lstm_gates_kernel<<<G4 / 4, 256, 0, stream>>>(
            W_ih + l * Wstride, W_hh + l * Wstride,
            b_ih + (size_t)l * G4, b_hh + (size_t)l * G4,
            cur_x, h0 + (size_t)l * H, gates);

        lstm_update_kernel<<<H / 256, 256, 0, stream>>>(
            gates, c0 + (size_t)l * H,
            last ? out : xbuf,
            nullptr);

        cur_x = xbuf;
    }
}

// Round 2
// 396.576 us; speedup vs baseline: 1.0397x; 1.0397x over previous
//
#include <hip/hip_runtime.h>
#include <math.h>

#define H 2048
#define R (4 * H)          // 8192 rows per weight matrix
#define L 3

// ---------------------------------------------------------------------------
// Block-per-row GEMV. 256 threads split the K=2048 dot product; each thread
// does 2 float4 loads of the row (coalesced, 8 KB/block) and 2 of the vector
// (L2-resident). Two-stage reduce: 64-lane shuffle, then 4 partials via LDS.
// ---------------------------------------------------------------------------

__device__ __forceinline__ float block_row_dot(const float* __restrict__ row,
                                               const float* __restrict__ vec,
                                               int t) {
    const float4* r4 = (const float4*)row;
    const float4* v4 = (const float4*)vec;
    float acc = 0.f;
#pragma unroll
    for (int it = 0; it < (H / 4) / 256; ++it) {   // 2 iterations
        const int idx = it * 256 + t;
        float4 a = r4[idx];
        float4 v = v4[idx];
        acc += a.x * v.x + a.y * v.y + a.z * v.z + a.w * v.w;
    }
#pragma unroll
    for (int off = 32; off > 0; off >>= 1)
        acc += __shfl_down(acc, off);
    __shared__ float s[4];
    if ((t & 63) == 0) s[t >> 6] = acc;
    __syncthreads();
    return s[0] + s[1] + s[2] + s[3];   // valid in all threads after sync
}

// Phase 1: all input-independent GEMV rows in one launch.
//   blk in [0, R):          xpart[blk]  = Wi[0][blk,:] @ x
//   blk in [R, R + 3R):     pre[r]      = Wh[l][rr,:] @ h0[l] + bi[r] + bh[r]
//                           where r = blk - R, l = r / R, rr = r % R
__global__ __launch_bounds__(256) void phase1_kernel(
    const float* __restrict__ Wi0,   // [R, H]
    const float* __restrict__ Wh,    // [L, R, H]
    const float* __restrict__ bi,    // [L*R]
    const float* __restrict__ bh,    // [L*R]
    const float* __restrict__ x,     // [H]
    const float* __restrict__ h0,    // [L, H]
    float* __restrict__ xpart,       // [R]
    float* __restrict__ pre)         // [L*R]
{
    const int blk = blockIdx.x;
    const int t = threadIdx.x;

    const float* row;
    const float* vec;
    if (blk < R) {
        row = Wi0 + (size_t)blk * H;
        vec = x;
    } else {
        const int r = blk - R;
        const int l = r >> 13;            // / 8192
        row = Wh + (size_t)r * H;         // Wh is [L*R, H] flat
        vec = h0 + l * H;
    }

    const float tot = block_row_dot(row, vec, t);

    if (t == 0) {
        if (blk < R) {
            xpart[blk] = tot;
        } else {
            const int r = blk - R;
            pre[r] = tot + bi[r] + bh[r];
        }
    }
}

// Phases 2/3: Wi[l] @ x_l  (no bias; bias lives in pre[])
__global__ __launch_bounds__(256) void wix_kernel(
    const float* __restrict__ Wi,    // [R, H] this layer
    const float* __restrict__ x,     // [H]
    float* __restrict__ xpart)       // [R]
{
    const int blk = blockIdx.x;
    const int t = threadIdx.x;
    const float tot = block_row_dot(Wi + (size_t)blk * H, x, t);
    if (t == 0) xpart[blk] = tot;
}

// Elementwise LSTM cell update.
__global__ __launch_bounds__(256) void update_kernel(
    const float* __restrict__ pre_l,  // [R] Wh@h + biases, gate order i,f,g,o
    const float* __restrict__ xpart,  // [R] Wi@x
    const float* __restrict__ c0_l,   // [H]
    float* __restrict__ h_out)        // [H]
{
    const int j = blockIdx.x * blockDim.x + threadIdx.x;
    if (j >= H) return;

    const float gi = pre_l[j]         + xpart[j];
    const float gf = pre_l[H + j]     + xpart[H + j];
    const float gg = pre_l[2 * H + j] + xpart[2 * H + j];
    const float go = pre_l[3 * H + j] + xpart[3 * H + j];

    const float i_ = 1.f / (1.f + expf(-gi));
    const float f_ = 1.f / (1.f + expf(-gf));
    const float g_ = tanhf(gg);
    const float o_ = 1.f / (1.f + expf(-go));

    const float c_new = f_ * c0_l[j] + i_ * g_;
    h_out[j] = o_ * tanhf(c_new);
}

extern "C" void kernel_launch(void* const* d_in, const int* in_sizes, int n_in,
                              void* d_out, int out_size, void* d_ws, size_t ws_size,
                              hipStream_t stream) {
    const float* x    = (const float*)d_in[0];  // [H]
    const float* W_ih = (const float*)d_in[1];  // [L, R, H]
    const float* W_hh = (const float*)d_in[2];  // [L, R, H]
    const float* b_ih = (const float*)d_in[3];  // [L, R]
    const float* b_hh = (const float*)d_in[4];  // [L, R]
    const float* h0   = (const float*)d_in[5];  // [L, H]
    const float* c0   = (const float*)d_in[6];  // [L, H]
    float* out = (float*)d_out;                 // [H]

    float* xpart = (float*)d_ws;                // [R]
    float* pre   = xpart + R;                   // [L*R]
    float* xbuf1 = pre + L * R;                 // [H]
    float* xbuf2 = xbuf1 + H;                   // [H]

    const size_t Wstride = (size_t)R * H;

    // Phase 1: Wi[0]@x and all Wh[l]@h0[l] (+biases) — 268 MB in one launch.
    phase1_kernel<<<R + L * R, 256, 0, stream>>>(
        W_ih, W_hh, b_ih, b_hh, x, h0, xpart, pre);

    // Layer 0 update -> xbuf1
    update_kernel<<<H / 256, 256, 0, stream>>>(pre, xpart, c0, xbuf1);

    // Phase 2: Wi[1] @ xbuf1
    wix_kernel<<<R, 256, 0, stream>>>(W_ih + Wstride, xbuf1, xpart);
    update_kernel<<<H / 256, 256, 0, stream>>>(pre + R, xpart, c0 + H, xbuf2);

    // Phase 3: Wi[2] @ xbuf2
    wix_kernel<<<R, 256, 0, stream>>>(W_ih + 2 * Wstride, xbuf2, xpart);
    update_kernel<<<H / 256, 256, 0, stream>>>(pre + 2 * R, xpart, c0 + 2 * H, out);
}